// Round 18
// baseline (117.237 us; speedup 1.0000x reference)
//
#include <hip/hip_runtime.h>
#include <hip/hip_bf16.h>
#include <math.h>

typedef __attribute__((ext_vector_type(8))) short bf16x8;
typedef __attribute__((ext_vector_type(4))) float f32x4;

__device__ __forceinline__ unsigned short f2bf(float f) {
    unsigned u = __float_as_uint(f);
    unsigned r = ((u >> 16) & 1u) + 0x7fffu;   // RNE
    return (unsigned short)((u + r) >> 16);
}
__device__ __forceinline__ float bfL(unsigned u) { return __uint_as_float(u << 16); }
__device__ __forceinline__ float bfH(unsigned u) { return __uint_as_float(u & 0xffff0000u); }

#define SCORE_NPB 128   // nodes per score block (4 groups of 32, 8 lanes/node)

// ---- prep: W->bf16 frags | scores (fp32 exact) | head4 init ----------------
__global__ __launch_bounds__(256) void k_prep(const float* __restrict__ W,
                                              const float* __restrict__ bias,
                                              const float* __restrict__ att,
                                              const float* __restrict__ h,
                                              unsigned short* __restrict__ Wb16,
                                              float* __restrict__ s_src,
                                              float* __restrict__ s_dst,
                                              int* __restrict__ head4,
                                              int N, int scoreBlocks) {
    const int t = threadIdx.x;
    const int bid = blockIdx.x;
    if (bid == 0) {
        // W -> bf16 MFMA fragment order (granule gi = kg*128 + row;
        // k = (kg>>2)*32 + (e>>2)*16 + (kg&3)*4 + (e&3))
#pragma unroll
        for (int q = 0; q < 8; ++q) {
            int gi = q * 256 + t;
            int kg = gi >> 7, row = gi & 127;
            int kbase = (kg >> 2) * 32 + (kg & 3) * 4;
            unsigned pk[4];
#pragma unroll
            for (int p = 0; p < 4; ++p) {
                int e0 = 2 * p, e1 = 2 * p + 1;
                float v0 = W[(size_t)row * 128 + kbase + (e0 >> 2) * 16 + (e0 & 3)];
                float v1 = W[(size_t)row * 128 + kbase + (e1 >> 2) * 16 + (e1 & 3)];
                pk[p] = ((unsigned)f2bf(v1) << 16) | f2bf(v0);
            }
            *reinterpret_cast<uint4*>(&Wb16[(size_t)gi * 8]) =
                make_uint4(pk[0], pk[1], pk[2], pk[3]);
        }
    } else if (bid <= scoreBlocks) {
        // fp32 score halves: fold wsd = W^T att in LDS once, score 128 nodes
        __shared__ float wsdL[2][4][128];   // [isDst][head][k], 4 KB
        __shared__ float cs[8];
#pragma unroll
        for (int q = 0; q < 4; ++q) {
            int idx = q * 256 + t;          // 1024 entries
            int isD = idx >> 9, rem = idx & 511;
            int hd = rem >> 7, k = rem & 127;
            float w = 0.f;
            for (int j = 0; j < 32; ++j)
                w += W[(size_t)(hd * 32 + j) * 128 + k] * att[hd * 65 + isD * 32 + j];
            wsdL[isD][hd][k] = w;
        }
        if (t < 8) {
            int chd = t & 3, cIsD = t >> 2;
            float c = 0.f;
            for (int j = 0; j < 32; ++j)
                c += bias[chd * 32 + j] * att[chd * 65 + cIsD * 32 + j];
            cs[t] = c;
        }
        __syncthreads();
        const int p = t & 7;
#pragma unroll
        for (int it = 0; it < 4; ++it) {
            int node = (bid - 1) * SCORE_NPB + it * 32 + (t >> 3);
            if (node >= N) continue;
            const float* hp = h + (size_t)node * 128 + p * 16;
            float ss[4] = {0.f, 0.f, 0.f, 0.f}, sd[4] = {0.f, 0.f, 0.f, 0.f};
#pragma unroll
            for (int q = 0; q < 4; ++q) {
                float4 hv = *reinterpret_cast<const float4*>(hp + q * 4);
#pragma unroll
                for (int hd = 0; hd < 4; ++hd) {
                    const float* wa = &wsdL[0][hd][p * 16 + q * 4];
                    const float* wb = &wsdL[1][hd][p * 16 + q * 4];
                    ss[hd] += hv.x * wa[0] + hv.y * wa[1] + hv.z * wa[2] + hv.w * wa[3];
                    sd[hd] += hv.x * wb[0] + hv.y * wb[1] + hv.z * wb[2] + hv.w * wb[3];
                }
            }
#pragma unroll
            for (int off = 1; off < 8; off <<= 1)
#pragma unroll
                for (int hd = 0; hd < 4; ++hd) {
                    ss[hd] += __shfl_xor(ss[hd], off);
                    sd[hd] += __shfl_xor(sd[hd], off);
                }
            if (p == 0) {
                *reinterpret_cast<float4*>(&s_src[(size_t)node * 4]) =
                    make_float4(ss[0] + cs[0], ss[1] + cs[1], ss[2] + cs[2], ss[3] + cs[3]);
                *reinterpret_cast<float4*>(&s_dst[(size_t)node * 4]) =
                    make_float4(sd[0] + cs[4], sd[1] + cs[5], sd[2] + cs[6], sd[3] + cs[7]);
            }
        }
    } else {
        int i = ((bid - 1 - scoreBlocks) * 256 + t) * 4;
        if (i < N * 4)
            *reinterpret_cast<int4*>(&head4[i]) = make_int4(-1, -1, -1, -1);
    }
}

// ---- work: MFMA GEMM blocks + edge blocks (fused, independent) -------------
__global__ __launch_bounds__(256) void k_work(
        const float* __restrict__ h, const unsigned short* __restrict__ Wb16,
        const float* __restrict__ bias, unsigned short* __restrict__ zb16,
        const int* __restrict__ src, const int* __restrict__ dst,
        const float* __restrict__ ef, const float* __restrict__ att,
        const float* __restrict__ s_src, const float* __restrict__ s_dst,
        int* __restrict__ head4, int4* __restrict__ epkt,
        int N, int E, int gemmBlocks) {
    __shared__ short hS[16 * 64 * 8];    // 16 KB (gemm blocks only)
    const int t = threadIdx.x;
    const int bid = blockIdx.x;

    if (bid >= gemmBlocks) {
        // ---- edge: alpha (dense) + linked-list build (4 chains/node) ----
        int e = (bid - gemmBlocks) * 256 + t;
        if (e >= E) return;
        int s = src[e], d = dst[e];
        float fv = ef[e];
        // issue the atomic FIRST: its ~400cy round-trip overlaps the gathers
        int prev = atomicExch(&head4[(size_t)d * 4 + (e & 3)], e);
        float4 ss = *reinterpret_cast<const float4*>(&s_src[(size_t)s * 4]);
        float4 sd = *reinterpret_cast<const float4*>(&s_dst[(size_t)d * 4]);
        float aE0 = att[64], aE1 = att[129], aE2 = att[194], aE3 = att[259];
        float sc0 = ss.x + sd.x + fv * aE0;
        float sc1 = ss.y + sd.y + fv * aE1;
        float sc2 = ss.z + sd.z + fv * aE2;
        float sc3 = ss.w + sd.w + fv * aE3;
        sc0 = sc0 >= 0.f ? sc0 : 0.2f * sc0;  sc1 = sc1 >= 0.f ? sc1 : 0.2f * sc1;
        sc2 = sc2 >= 0.f ? sc2 : 0.2f * sc2;  sc3 = sc3 >= 0.f ? sc3 : 0.2f * sc3;
        float a0 = expf(fminf(fmaxf(sc0, -20.f), 20.f));
        float a1 = expf(fminf(fmaxf(sc1, -20.f), 20.f));
        float a2 = expf(fminf(fmaxf(sc2, -20.f), 20.f));
        float a3 = expf(fminf(fmaxf(sc3, -20.f), 20.f));
        epkt[e] = make_int4(s, prev,
            (int)(((unsigned)f2bf(a1) << 16) | f2bf(a0)),
            (int)(((unsigned)f2bf(a3) << 16) | f2bf(a2)));
        return;
    }

    // ---- GEMM block: 64 nodes x 64 cols (bid&1 selects col half) ----
    const int by = bid & 1;
    const int n0 = (bid >> 1) * 64;
    const int obase = by * 64;
#pragma unroll
    for (int q = 0; q < 8; ++q) {
        int f = q * 256 + t;
        int nd = f >> 5;
        int k4 = (f & 31) * 4;
        int ks = k4 >> 5, rr = k4 & 31;
        int half = rr >> 4, g = (rr & 15) >> 2;
        int kg = ks * 4 + g;
        int slot = kg * 64 + (nd ^ (kg & 7));
        int hn = n0 + nd; if (hn > N - 1) hn = N - 1;
        float4 v = *reinterpret_cast<const float4*>(&h[(size_t)hn * 128 + k4]);
        uint2 pk = make_uint2(((unsigned)f2bf(v.y) << 16) | f2bf(v.x),
                              ((unsigned)f2bf(v.w) << 16) | f2bf(v.z));
        *reinterpret_cast<uint2*>(&hS[slot * 8 + half * 4]) = pk;
    }
    __syncthreads();

    const int wv = t >> 6, l = t & 63;
    const int la = l & 15, lb = l >> 4;
    const int nbase = wv * 16;
    const int node = n0 + nbase + la;

    bf16x8 hfr[4];
#pragma unroll
    for (int ks = 0; ks < 4; ++ks) {
        int kg = ks * 4 + lb;
        int slot = kg * 64 + ((nbase + la) ^ (kg & 7));
        hfr[ks] = *reinterpret_cast<const bf16x8*>(&hS[slot * 8]);
    }

#pragma unroll
    for (int ot = 0; ot < 4; ++ot) {
        f32x4 acc = {0.f, 0.f, 0.f, 0.f};
#pragma unroll
        for (int ks = 0; ks < 4; ++ks) {
            int kg = ks * 4 + lb;
            bf16x8 wfr = *reinterpret_cast<const bf16x8*>(
                &Wb16[((size_t)kg * 128 + obase + ot * 16 + la) * 8]);
            acc = __builtin_amdgcn_mfma_f32_16x16x32_bf16(wfr, hfr[ks], acc, 0, 0, 0);
        }
        int colb = obase + ot * 16 + lb * 4;
        float4 bq = *reinterpret_cast<const float4*>(&bias[colb]);
        if (node < N) {
            uint2 pk = make_uint2(
                ((unsigned)f2bf(acc[1] + bq.y) << 16) | f2bf(acc[0] + bq.x),
                ((unsigned)f2bf(acc[3] + bq.w) << 16) | f2bf(acc[2] + bq.z));
            *reinterpret_cast<uint2*>(&zb16[(size_t)node * 128 + colb]) = pk;
        }
    }
}

// ---- fused: 4-chain walk aggregate + residual + LN + ELU -------------------
// 16 nodes per wave (4 lanes/node, 32 channels/lane = head l4); 4 chains/node.
// 128-thread blocks (2 waves, 32 nodes).
__global__ __launch_bounds__(128) void k_agg_final(const int* __restrict__ head4,
                                                   const int4* __restrict__ epkt,
                                                   const uint4* __restrict__ zb4,
                                                   const float* __restrict__ g,
                                                   const float* __restrict__ bparm,
                                                   float* __restrict__ out, int N) {
    int wave = threadIdx.x >> 6, lane = threadIdx.x & 63;
    int l4 = lane & 3;
    int n = blockIdx.x * 32 + wave * 16 + (lane >> 2);
    if (n >= N) return;
    const int hd = l4;                  // head of channels l4*32..+31
    int4 eh = *reinterpret_cast<const int4*>(&head4[(size_t)n * 4]);
    int e0 = eh.x, e1 = eh.y, e2 = eh.z, e3 = eh.w;
    float X[32];
#pragma unroll
    for (int i = 0; i < 32; ++i) X[i] = 0.f;
    float da = 0.f;
#define UNPK(P, AV) { unsigned u = (hd & 2) ? (unsigned)(P).w : (unsigned)(P).z; \
    AV = (hd & 1) ? bfH(u) : bfL(u); }
#define STEP(EV) if (EV != -1) { \
        int4 p = epkt[EV]; \
        uint4 q0 = zb4[(size_t)p.x * 16 + l4 * 4 + 0]; \
        uint4 q1 = zb4[(size_t)p.x * 16 + l4 * 4 + 1]; \
        uint4 q2 = zb4[(size_t)p.x * 16 + l4 * 4 + 2]; \
        uint4 q3 = zb4[(size_t)p.x * 16 + l4 * 4 + 3]; \
        float a; UNPK(p, a) \
        X[0]  += bfL(q0.x) * a; X[1]  += bfH(q0.x) * a; \
        X[2]  += bfL(q0.y) * a; X[3]  += bfH(q0.y) * a; \
        X[4]  += bfL(q0.z) * a; X[5]  += bfH(q0.z) * a; \
        X[6]  += bfL(q0.w) * a; X[7]  += bfH(q0.w) * a; \
        X[8]  += bfL(q1.x) * a; X[9]  += bfH(q1.x) * a; \
        X[10] += bfL(q1.y) * a; X[11] += bfH(q1.y) * a; \
        X[12] += bfL(q1.z) * a; X[13] += bfH(q1.z) * a; \
        X[14] += bfL(q1.w) * a; X[15] += bfH(q1.w) * a; \
        X[16] += bfL(q2.x) * a; X[17] += bfH(q2.x) * a; \
        X[18] += bfL(q2.y) * a; X[19] += bfH(q2.y) * a; \
        X[20] += bfL(q2.z) * a; X[21] += bfH(q2.z) * a; \
        X[22] += bfL(q2.w) * a; X[23] += bfH(q2.w) * a; \
        X[24] += bfL(q3.x) * a; X[25] += bfH(q3.x) * a; \
        X[26] += bfL(q3.y) * a; X[27] += bfH(q3.y) * a; \
        X[28] += bfL(q3.z) * a; X[29] += bfH(q3.z) * a; \
        X[30] += bfL(q3.w) * a; X[31] += bfH(q3.w) * a; \
        da += a; EV = p.y; }
    while (((e0 & e1) & (e2 & e3)) != -1) {
        STEP(e0) STEP(e1) STEP(e2) STEP(e3)
    }
#undef STEP
#undef UNPK

    float inv = 1.f / (da + 1e-6f);
    // residual from zb (4 uint4 = this lane's 32 channels)
    float s = 0.f;
#pragma unroll
    for (int qi = 0; qi < 4; ++qi) {
        uint4 qz = zb4[(size_t)n * 16 + l4 * 4 + qi];
        int b = qi * 8;
        X[b + 0] = X[b + 0] * inv + bfL(qz.x);
        X[b + 1] = X[b + 1] * inv + bfH(qz.x);
        X[b + 2] = X[b + 2] * inv + bfL(qz.y);
        X[b + 3] = X[b + 3] * inv + bfH(qz.y);
        X[b + 4] = X[b + 4] * inv + bfL(qz.z);
        X[b + 5] = X[b + 5] * inv + bfH(qz.z);
        X[b + 6] = X[b + 6] * inv + bfL(qz.w);
        X[b + 7] = X[b + 7] * inv + bfH(qz.w);
#pragma unroll
        for (int j = 0; j < 8; ++j) s += X[b + j];
    }
#pragma unroll
    for (int off = 1; off < 4; off <<= 1) s += __shfl_xor(s, off);
    float mu = s * (1.f / 128.f);
    float q = 0.f;
#pragma unroll
    for (int i = 0; i < 32; ++i) {
        X[i] -= mu;
        q += X[i] * X[i];
    }
#pragma unroll
    for (int off = 1; off < 4; off <<= 1) q += __shfl_xor(q, off);
    float rstd = rsqrtf(q * (1.f / 128.f) + 1e-5f);
    const int c = l4 * 32;
#pragma unroll
    for (int qb = 0; qb < 8; ++qb) {
        float4 gg = *reinterpret_cast<const float4*>(&g[c + qb * 4]);
        float4 bb = *reinterpret_cast<const float4*>(&bparm[c + qb * 4]);
        float y0 = X[qb * 4 + 0] * rstd * gg.x + bb.x;
        float y1 = X[qb * 4 + 1] * rstd * gg.y + bb.y;
        float y2 = X[qb * 4 + 2] * rstd * gg.z + bb.z;
        float y3 = X[qb * 4 + 3] * rstd * gg.w + bb.w;
        y0 = y0 > 0.f ? y0 : expf(y0) - 1.f;
        y1 = y1 > 0.f ? y1 : expf(y1) - 1.f;
        y2 = y2 > 0.f ? y2 : expf(y2) - 1.f;
        y3 = y3 > 0.f ? y3 : expf(y3) - 1.f;
        *reinterpret_cast<float4*>(&out[(size_t)n * 128 + c + qb * 4]) =
            make_float4(y0, y1, y2, y3);
    }
}

extern "C" void kernel_launch(void* const* d_in, const int* in_sizes, int n_in,
                              void* d_out, int out_size, void* d_ws, size_t ws_size,
                              hipStream_t stream) {
    const float* h   = (const float*)d_in[0];
    const int*   ei  = (const int*)d_in[1];
    const float* ef  = (const float*)d_in[2];
    const float* Ww  = (const float*)d_in[3];
    const float* Wb  = (const float*)d_in[4];
    const float* att = (const float*)d_in[5];
    const float* lng = (const float*)d_in[6];
    const float* lnb = (const float*)d_in[7];
    float* out = (float*)d_out;

    const int N = in_sizes[0] / 128;   // 50000
    const int E = in_sizes[1] / 2;     // 800000
    const int* src = ei;
    const int* dst = ei + E;

    char* ws = (char*)d_ws;
    unsigned short* zb16   = (unsigned short*)ws; ws += (size_t)N * 128 * 2;
    unsigned short* Wb16   = (unsigned short*)ws; ws += (size_t)128 * 128 * 2;
    float*          s_src  = (float*)ws;          ws += (size_t)N * 4 * 4;
    float*          s_dst  = (float*)ws;          ws += (size_t)N * 4 * 4;
    int*            head4  = (int*)ws;            ws += (size_t)N * 4 * 4;
    int4*           epkt   = (int4*)ws;           ws += (size_t)E * 16;

    const int scoreBlocks = (N + SCORE_NPB - 1) / SCORE_NPB;   // 391
    const int headBlocks  = (N + 255) / 256;                   // 196
    k_prep<<<1 + scoreBlocks + headBlocks, 256, 0, stream>>>(
        Ww, Wb, att, h, Wb16, s_src, s_dst, head4, N, scoreBlocks);

    const int gemmBlocks = ((N + 63) / 64) * 2;   // 1564
    const int edgeBlocks = (E + 255) / 256;       // 3125
    k_work<<<gemmBlocks + edgeBlocks, 256, 0, stream>>>(
        h, Wb16, Wb, zb16, src, dst, ef, att, s_src, s_dst, head4, epkt,
        N, E, gemmBlocks);
    k_agg_final<<<(N + 31) / 32, 128, 0, stream>>>(head4, epkt,
                                                   (const uint4*)zb16, lng, lnb, out, N);
}

// Round 19
// 114.079 us; speedup vs baseline: 1.0277x; 1.0277x over previous
//
#include <hip/hip_runtime.h>
#include <hip/hip_bf16.h>
#include <math.h>

typedef __attribute__((ext_vector_type(8))) short bf16x8;
typedef __attribute__((ext_vector_type(4))) float f32x4;

__device__ __forceinline__ unsigned short f2bf(float f) {
    unsigned u = __float_as_uint(f);
    unsigned r = ((u >> 16) & 1u) + 0x7fffu;   // RNE
    return (unsigned short)((u + r) >> 16);
}
__device__ __forceinline__ float bfL(unsigned u) { return __uint_as_float(u << 16); }
__device__ __forceinline__ float bfH(unsigned u) { return __uint_as_float(u & 0xffff0000u); }

#define SCORE_NPB 128   // nodes per score block (4 groups of 32, 8 lanes/node)

// ---- prep: W->bf16 frags | scores (fp32 exact) | head4 init ----------------
__global__ __launch_bounds__(256) void k_prep(const float* __restrict__ W,
                                              const float* __restrict__ bias,
                                              const float* __restrict__ att,
                                              const float* __restrict__ h,
                                              unsigned short* __restrict__ Wb16,
                                              float* __restrict__ s_src,
                                              float* __restrict__ s_dst,
                                              int* __restrict__ head4,
                                              int N, int scoreBlocks) {
    const int t = threadIdx.x;
    const int bid = blockIdx.x;
    if (bid == 0) {
        // W -> bf16 MFMA fragment order (granule gi = kg*128 + row;
        // k = (kg>>2)*32 + (e>>2)*16 + (kg&3)*4 + (e&3))
#pragma unroll
        for (int q = 0; q < 8; ++q) {
            int gi = q * 256 + t;
            int kg = gi >> 7, row = gi & 127;
            int kbase = (kg >> 2) * 32 + (kg & 3) * 4;
            unsigned pk[4];
#pragma unroll
            for (int p = 0; p < 4; ++p) {
                int e0 = 2 * p, e1 = 2 * p + 1;
                float v0 = W[(size_t)row * 128 + kbase + (e0 >> 2) * 16 + (e0 & 3)];
                float v1 = W[(size_t)row * 128 + kbase + (e1 >> 2) * 16 + (e1 & 3)];
                pk[p] = ((unsigned)f2bf(v1) << 16) | f2bf(v0);
            }
            *reinterpret_cast<uint4*>(&Wb16[(size_t)gi * 8]) =
                make_uint4(pk[0], pk[1], pk[2], pk[3]);
        }
    } else if (bid <= scoreBlocks) {
        // fp32 score halves: fold wsd = W^T att in LDS once, score 128 nodes
        __shared__ float wsdL[2][4][128];   // [isDst][head][k], 4 KB
        __shared__ float cs[8];
#pragma unroll
        for (int q = 0; q < 4; ++q) {
            int idx = q * 256 + t;          // 1024 entries
            int isD = idx >> 9, rem = idx & 511;
            int hd = rem >> 7, k = rem & 127;
            float w = 0.f;
            for (int j = 0; j < 32; ++j)
                w += W[(size_t)(hd * 32 + j) * 128 + k] * att[hd * 65 + isD * 32 + j];
            wsdL[isD][hd][k] = w;
        }
        if (t < 8) {
            int chd = t & 3, cIsD = t >> 2;
            float c = 0.f;
            for (int j = 0; j < 32; ++j)
                c += bias[chd * 32 + j] * att[chd * 65 + cIsD * 32 + j];
            cs[t] = c;
        }
        __syncthreads();
        const int p = t & 7;
#pragma unroll
        for (int it = 0; it < 4; ++it) {
            int node = (bid - 1) * SCORE_NPB + it * 32 + (t >> 3);
            if (node >= N) continue;
            const float* hp = h + (size_t)node * 128 + p * 16;
            float ss[4] = {0.f, 0.f, 0.f, 0.f}, sd[4] = {0.f, 0.f, 0.f, 0.f};
#pragma unroll
            for (int q = 0; q < 4; ++q) {
                float4 hv = *reinterpret_cast<const float4*>(hp + q * 4);
#pragma unroll
                for (int hd = 0; hd < 4; ++hd) {
                    const float* wa = &wsdL[0][hd][p * 16 + q * 4];
                    const float* wb = &wsdL[1][hd][p * 16 + q * 4];
                    ss[hd] += hv.x * wa[0] + hv.y * wa[1] + hv.z * wa[2] + hv.w * wa[3];
                    sd[hd] += hv.x * wb[0] + hv.y * wb[1] + hv.z * wb[2] + hv.w * wb[3];
                }
            }
#pragma unroll
            for (int off = 1; off < 8; off <<= 1)
#pragma unroll
                for (int hd = 0; hd < 4; ++hd) {
                    ss[hd] += __shfl_xor(ss[hd], off);
                    sd[hd] += __shfl_xor(sd[hd], off);
                }
            if (p == 0) {
                *reinterpret_cast<float4*>(&s_src[(size_t)node * 4]) =
                    make_float4(ss[0] + cs[0], ss[1] + cs[1], ss[2] + cs[2], ss[3] + cs[3]);
                *reinterpret_cast<float4*>(&s_dst[(size_t)node * 4]) =
                    make_float4(sd[0] + cs[4], sd[1] + cs[5], sd[2] + cs[6], sd[3] + cs[7]);
            }
        }
    } else {
        int i = ((bid - 1 - scoreBlocks) * 256 + t) * 4;
        if (i < N * 4)
            *reinterpret_cast<int4*>(&head4[i]) = make_int4(-1, -1, -1, -1);
    }
}

// ---- work: MFMA GEMM blocks + edge blocks (fused, independent) -------------
__global__ __launch_bounds__(256) void k_work(
        const float* __restrict__ h, const unsigned short* __restrict__ Wb16,
        const float* __restrict__ bias, unsigned short* __restrict__ zb16,
        const int* __restrict__ src, const int* __restrict__ dst,
        const float* __restrict__ ef, const float* __restrict__ att,
        const float* __restrict__ s_src, const float* __restrict__ s_dst,
        int* __restrict__ head4, int4* __restrict__ epkt,
        int N, int E, int gemmBlocks) {
    __shared__ short hS[16 * 64 * 8];    // 16 KB (gemm blocks only)
    const int t = threadIdx.x;
    const int bid = blockIdx.x;

    if (bid >= gemmBlocks) {
        // ---- edge: alpha (dense) + linked-list build (4 chains/node) ----
        int e = (bid - gemmBlocks) * 256 + t;
        if (e >= E) return;
        int s = src[e], d = dst[e];
        float fv = ef[e];
        // atomic FIRST: its round-trip overlaps the score gathers
        int prev = atomicExch(&head4[(size_t)d * 4 + (e & 3)], e);
        float4 ss = *reinterpret_cast<const float4*>(&s_src[(size_t)s * 4]);
        float4 sd = *reinterpret_cast<const float4*>(&s_dst[(size_t)d * 4]);
        float aE0 = att[64], aE1 = att[129], aE2 = att[194], aE3 = att[259];
        float sc0 = ss.x + sd.x + fv * aE0;
        float sc1 = ss.y + sd.y + fv * aE1;
        float sc2 = ss.z + sd.z + fv * aE2;
        float sc3 = ss.w + sd.w + fv * aE3;
        sc0 = sc0 >= 0.f ? sc0 : 0.2f * sc0;  sc1 = sc1 >= 0.f ? sc1 : 0.2f * sc1;
        sc2 = sc2 >= 0.f ? sc2 : 0.2f * sc2;  sc3 = sc3 >= 0.f ? sc3 : 0.2f * sc3;
        float a0 = expf(fminf(fmaxf(sc0, -20.f), 20.f));
        float a1 = expf(fminf(fmaxf(sc1, -20.f), 20.f));
        float a2 = expf(fminf(fmaxf(sc2, -20.f), 20.f));
        float a3 = expf(fminf(fmaxf(sc3, -20.f), 20.f));
        epkt[e] = make_int4(s, prev,
            (int)(((unsigned)f2bf(a1) << 16) | f2bf(a0)),
            (int)(((unsigned)f2bf(a3) << 16) | f2bf(a2)));
        return;
    }

    // ---- GEMM block: 64 nodes x 64 cols (bid&1 selects col half) ----
    const int by = bid & 1;
    const int n0 = (bid >> 1) * 64;
    const int obase = by * 64;
#pragma unroll
    for (int q = 0; q < 8; ++q) {
        int f = q * 256 + t;
        int nd = f >> 5;
        int k4 = (f & 31) * 4;
        int ks = k4 >> 5, rr = k4 & 31;
        int half = rr >> 4, g = (rr & 15) >> 2;
        int kg = ks * 4 + g;
        int slot = kg * 64 + (nd ^ (kg & 7));
        int hn = n0 + nd; if (hn > N - 1) hn = N - 1;
        float4 v = *reinterpret_cast<const float4*>(&h[(size_t)hn * 128 + k4]);
        uint2 pk = make_uint2(((unsigned)f2bf(v.y) << 16) | f2bf(v.x),
                              ((unsigned)f2bf(v.w) << 16) | f2bf(v.z));
        *reinterpret_cast<uint2*>(&hS[slot * 8 + half * 4]) = pk;
    }
    __syncthreads();

    const int wv = t >> 6, l = t & 63;
    const int la = l & 15, lb = l >> 4;
    const int nbase = wv * 16;
    const int node = n0 + nbase + la;

    bf16x8 hfr[4];
#pragma unroll
    for (int ks = 0; ks < 4; ++ks) {
        int kg = ks * 4 + lb;
        int slot = kg * 64 + ((nbase + la) ^ (kg & 7));
        hfr[ks] = *reinterpret_cast<const bf16x8*>(&hS[slot * 8]);
    }

#pragma unroll
    for (int ot = 0; ot < 4; ++ot) {
        f32x4 acc = {0.f, 0.f, 0.f, 0.f};
#pragma unroll
        for (int ks = 0; ks < 4; ++ks) {
            int kg = ks * 4 + lb;
            bf16x8 wfr = *reinterpret_cast<const bf16x8*>(
                &Wb16[((size_t)kg * 128 + obase + ot * 16 + la) * 8]);
            acc = __builtin_amdgcn_mfma_f32_16x16x32_bf16(wfr, hfr[ks], acc, 0, 0, 0);
        }
        int colb = obase + ot * 16 + lb * 4;
        float4 bq = *reinterpret_cast<const float4*>(&bias[colb]);
        if (node < N) {
            uint2 pk = make_uint2(
                ((unsigned)f2bf(acc[1] + bq.y) << 16) | f2bf(acc[0] + bq.x),
                ((unsigned)f2bf(acc[3] + bq.w) << 16) | f2bf(acc[2] + bq.z));
            *reinterpret_cast<uint2*>(&zb16[(size_t)node * 128 + colb]) = pk;
        }
    }
}

// ---- fused: pipelined 4-chain walk + residual + LN + ELU -------------------
// 8 nodes per wave (8 lanes/node, 16 channels/lane); 4 chains per node.
// 128-thread blocks (2 waves, 16 nodes). 2-deep software pipeline: next
// packets are fetched while current packets' zb gathers + FMAs execute.
__global__ __launch_bounds__(128) void k_agg_final(const int* __restrict__ head4,
                                                   const int4* __restrict__ epkt,
                                                   const uint4* __restrict__ zb4,
                                                   const float* __restrict__ g,
                                                   const float* __restrict__ bparm,
                                                   float* __restrict__ out, int N) {
    int wave = threadIdx.x >> 6, lane = threadIdx.x & 63;
    int l8 = lane & 7;
    int n = blockIdx.x * 16 + wave * 8 + (lane >> 3);
    if (n >= N) return;
    const int hd = l8 >> 1;             // head of channels l8*16..+15
    int4 eh = *reinterpret_cast<const int4*>(&head4[(size_t)n * 4]);
    float X0 = 0.f, X1 = 0.f, X2 = 0.f, X3 = 0.f;
    float X4 = 0.f, X5 = 0.f, X6 = 0.f, X7 = 0.f;
    float X8 = 0.f, X9 = 0.f, Xa = 0.f, Xb = 0.f;
    float Xc = 0.f, Xd = 0.f, Xe = 0.f, Xf = 0.f;
    float da = 0.f;

    bool v0 = eh.x != -1, v1 = eh.y != -1, v2 = eh.z != -1, v3 = eh.w != -1;
    int4 p0, p1, p2, p3;
    if (v0) p0 = epkt[eh.x];
    if (v1) p1 = epkt[eh.y];
    if (v2) p2 = epkt[eh.z];
    if (v3) p3 = epkt[eh.w];

#define UNPK(P, AV) { unsigned u = (hd & 2) ? (unsigned)(P).w : (unsigned)(P).z; \
    AV = (hd & 1) ? bfH(u) : bfL(u); }
#define PROC(P) { \
        uint4 q0 = zb4[(size_t)(P).x * 16 + l8 * 2]; \
        uint4 q1 = zb4[(size_t)(P).x * 16 + l8 * 2 + 1]; \
        float a; UNPK(P, a) \
        X0 += bfL(q0.x) * a; X1 += bfH(q0.x) * a; \
        X2 += bfL(q0.y) * a; X3 += bfH(q0.y) * a; \
        X4 += bfL(q0.z) * a; X5 += bfH(q0.z) * a; \
        X6 += bfL(q0.w) * a; X7 += bfH(q0.w) * a; \
        X8 += bfL(q1.x) * a; X9 += bfH(q1.x) * a; \
        Xa += bfL(q1.y) * a; Xb += bfH(q1.y) * a; \
        Xc += bfL(q1.z) * a; Xd += bfH(q1.z) * a; \
        Xe += bfL(q1.w) * a; Xf += bfH(q1.w) * a; \
        da += a; }

    while (v0 || v1 || v2 || v3) {
        // stage A: issue next-packet loads (hop latency hides under stage B)
        int ne0 = v0 ? p0.y : -1;  bool nv0 = ne0 != -1;
        int ne1 = v1 ? p1.y : -1;  bool nv1 = ne1 != -1;
        int ne2 = v2 ? p2.y : -1;  bool nv2 = ne2 != -1;
        int ne3 = v3 ? p3.y : -1;  bool nv3 = ne3 != -1;
        int4 np0, np1, np2, np3;
        if (nv0) np0 = epkt[ne0];
        if (nv1) np1 = epkt[ne1];
        if (nv2) np2 = epkt[ne2];
        if (nv3) np3 = epkt[ne3];
        // stage B: process current packets
        if (v0) PROC(p0)
        if (v1) PROC(p1)
        if (v2) PROC(p2)
        if (v3) PROC(p3)
        p0 = np0; p1 = np1; p2 = np2; p3 = np3;
        v0 = nv0; v1 = nv1; v2 = nv2; v3 = nv3;
    }
#undef PROC
#undef UNPK

    float inv = 1.f / (da + 1e-6f);
    uint4 qz0 = zb4[(size_t)n * 16 + l8 * 2];
    uint4 qz1 = zb4[(size_t)n * 16 + l8 * 2 + 1];
    float x0 = X0 * inv + bfL(qz0.x), x1 = X1 * inv + bfH(qz0.x);
    float x2 = X2 * inv + bfL(qz0.y), x3 = X3 * inv + bfH(qz0.y);
    float x4 = X4 * inv + bfL(qz0.z), x5 = X5 * inv + bfH(qz0.z);
    float x6 = X6 * inv + bfL(qz0.w), x7 = X7 * inv + bfH(qz0.w);
    float x8 = X8 * inv + bfL(qz1.x), x9 = X9 * inv + bfH(qz1.x);
    float xa = Xa * inv + bfL(qz1.y), xb = Xb * inv + bfH(qz1.y);
    float xc = Xc * inv + bfL(qz1.z), xd = Xd * inv + bfH(qz1.z);
    float xe = Xe * inv + bfL(qz1.w), xf = Xf * inv + bfH(qz1.w);
    float s = (((x0 + x1) + (x2 + x3)) + ((x4 + x5) + (x6 + x7)))
            + (((x8 + x9) + (xa + xb)) + ((xc + xd) + (xe + xf)));
#pragma unroll
    for (int off = 1; off < 8; off <<= 1) s += __shfl_xor(s, off);
    float mu = s * (1.f / 128.f);
    float d0 = x0 - mu, d1 = x1 - mu, d2 = x2 - mu, d3 = x3 - mu;
    float d4 = x4 - mu, d5 = x5 - mu, d6 = x6 - mu, d7 = x7 - mu;
    float d8 = x8 - mu, d9 = x9 - mu, dA = xa - mu, dB = xb - mu;
    float dC = xc - mu, dD = xd - mu, dE = xe - mu, dF = xf - mu;
    float q = (((d0 * d0 + d1 * d1) + (d2 * d2 + d3 * d3))
             + ((d4 * d4 + d5 * d5) + (d6 * d6 + d7 * d7)))
            + (((d8 * d8 + d9 * d9) + (dA * dA + dB * dB))
             + ((dC * dC + dD * dD) + (dE * dE + dF * dF)));
#pragma unroll
    for (int off = 1; off < 8; off <<= 1) q += __shfl_xor(q, off);
    float rstd = rsqrtf(q * (1.f / 128.f) + 1e-5f);
    const int c = l8 * 16;
    float dv[16] = {d0, d1, d2, d3, d4, d5, d6, d7, d8, d9, dA, dB, dC, dD, dE, dF};
#pragma unroll
    for (int qb = 0; qb < 4; ++qb) {
        float4 gg = *reinterpret_cast<const float4*>(&g[c + qb * 4]);
        float4 bb = *reinterpret_cast<const float4*>(&bparm[c + qb * 4]);
        float y0 = dv[qb * 4 + 0] * rstd * gg.x + bb.x;
        float y1 = dv[qb * 4 + 1] * rstd * gg.y + bb.y;
        float y2 = dv[qb * 4 + 2] * rstd * gg.z + bb.z;
        float y3 = dv[qb * 4 + 3] * rstd * gg.w + bb.w;
        y0 = y0 > 0.f ? y0 : expf(y0) - 1.f;
        y1 = y1 > 0.f ? y1 : expf(y1) - 1.f;
        y2 = y2 > 0.f ? y2 : expf(y2) - 1.f;
        y3 = y3 > 0.f ? y3 : expf(y3) - 1.f;
        *reinterpret_cast<float4*>(&out[(size_t)n * 128 + c + qb * 4]) =
            make_float4(y0, y1, y2, y3);
    }
}

extern "C" void kernel_launch(void* const* d_in, const int* in_sizes, int n_in,
                              void* d_out, int out_size, void* d_ws, size_t ws_size,
                              hipStream_t stream) {
    const float* h   = (const float*)d_in[0];
    const int*   ei  = (const int*)d_in[1];
    const float* ef  = (const float*)d_in[2];
    const float* Ww  = (const float*)d_in[3];
    const float* Wb  = (const float*)d_in[4];
    const float* att = (const float*)d_in[5];
    const float* lng = (const float*)d_in[6];
    const float* lnb = (const float*)d_in[7];
    float* out = (float*)d_out;

    const int N = in_sizes[0] / 128;   // 50000
    const int E = in_sizes[1] / 2;     // 800000
    const int* src = ei;
    const int* dst = ei + E;

    char* ws = (char*)d_ws;
    unsigned short* zb16   = (unsigned short*)ws; ws += (size_t)N * 128 * 2;
    unsigned short* Wb16   = (unsigned short*)ws; ws += (size_t)128 * 128 * 2;
    float*          s_src  = (float*)ws;          ws += (size_t)N * 4 * 4;
    float*          s_dst  = (float*)ws;          ws += (size_t)N * 4 * 4;
    int*            head4  = (int*)ws;            ws += (size_t)N * 4 * 4;
    int4*           epkt   = (int4*)ws;           ws += (size_t)E * 16;

    const int scoreBlocks = (N + SCORE_NPB - 1) / SCORE_NPB;   // 391
    const int headBlocks  = (N + 255) / 256;                   // 196
    k_prep<<<1 + scoreBlocks + headBlocks, 256, 0, stream>>>(
        Ww, Wb, att, h, Wb16, s_src, s_dst, head4, N, scoreBlocks);

    const int gemmBlocks = ((N + 63) / 64) * 2;   // 1564
    const int edgeBlocks = (E + 255) / 256;       // 3125
    k_work<<<gemmBlocks + edgeBlocks, 256, 0, stream>>>(
        h, Wb16, Wb, zb16, src, dst, ef, att, s_src, s_dst, head4, epkt,
        N, E, gemmBlocks);
    k_agg_final<<<(N + 15) / 16, 128, 0, stream>>>(head4, epkt,
                                                   (const uint4*)zb16, lng, lnb, out, N);
}

// Round 20
// 110.236 us; speedup vs baseline: 1.0635x; 1.0349x over previous
//
#include <hip/hip_runtime.h>
#include <hip/hip_bf16.h>
#include <math.h>

typedef __attribute__((ext_vector_type(8))) short bf16x8;
typedef __attribute__((ext_vector_type(4))) float f32x4;

__device__ __forceinline__ unsigned short f2bf(float f) {
    unsigned u = __float_as_uint(f);
    unsigned r = ((u >> 16) & 1u) + 0x7fffu;   // RNE
    return (unsigned short)((u + r) >> 16);
}
__device__ __forceinline__ float bfL(unsigned u) { return __uint_as_float(u << 16); }
__device__ __forceinline__ float bfH(unsigned u) { return __uint_as_float(u & 0xffff0000u); }

#define SCORE_NPB 128   // nodes per score block (4 groups of 32, 8 lanes/node)

// ---- prep: W->bf16 frags | scores (fp32 exact) | head4 init ----------------
__global__ __launch_bounds__(256) void k_prep(const float* __restrict__ W,
                                              const float* __restrict__ bias,
                                              const float* __restrict__ att,
                                              const float* __restrict__ h,
                                              unsigned short* __restrict__ Wb16,
                                              float* __restrict__ s_src,
                                              float* __restrict__ s_dst,
                                              int* __restrict__ head4,
                                              int N, int scoreBlocks) {
    const int t = threadIdx.x;
    const int bid = blockIdx.x;
    if (bid == 0) {
        // W -> bf16 MFMA fragment order (granule gi = kg*128 + row;
        // k = (kg>>2)*32 + (e>>2)*16 + (kg&3)*4 + (e&3))
#pragma unroll
        for (int q = 0; q < 8; ++q) {
            int gi = q * 256 + t;
            int kg = gi >> 7, row = gi & 127;
            int kbase = (kg >> 2) * 32 + (kg & 3) * 4;
            unsigned pk[4];
#pragma unroll
            for (int p = 0; p < 4; ++p) {
                int e0 = 2 * p, e1 = 2 * p + 1;
                float v0 = W[(size_t)row * 128 + kbase + (e0 >> 2) * 16 + (e0 & 3)];
                float v1 = W[(size_t)row * 128 + kbase + (e1 >> 2) * 16 + (e1 & 3)];
                pk[p] = ((unsigned)f2bf(v1) << 16) | f2bf(v0);
            }
            *reinterpret_cast<uint4*>(&Wb16[(size_t)gi * 8]) =
                make_uint4(pk[0], pk[1], pk[2], pk[3]);
        }
    } else if (bid <= scoreBlocks) {
        // fp32 score halves: fold wsd = W^T att in LDS once, score 128 nodes
        __shared__ float wsdL[2][4][128];   // [isDst][head][k], 4 KB
        __shared__ float cs[8];
#pragma unroll
        for (int q = 0; q < 4; ++q) {
            int idx = q * 256 + t;          // 1024 entries
            int isD = idx >> 9, rem = idx & 511;
            int hd = rem >> 7, k = rem & 127;
            float w = 0.f;
            for (int j = 0; j < 32; ++j)
                w += W[(size_t)(hd * 32 + j) * 128 + k] * att[hd * 65 + isD * 32 + j];
            wsdL[isD][hd][k] = w;
        }
        if (t < 8) {
            int chd = t & 3, cIsD = t >> 2;
            float c = 0.f;
            for (int j = 0; j < 32; ++j)
                c += bias[chd * 32 + j] * att[chd * 65 + cIsD * 32 + j];
            cs[t] = c;
        }
        __syncthreads();
        const int p = t & 7;
#pragma unroll
        for (int it = 0; it < 4; ++it) {
            int node = (bid - 1) * SCORE_NPB + it * 32 + (t >> 3);
            if (node >= N) continue;
            const float* hp = h + (size_t)node * 128 + p * 16;
            float ss[4] = {0.f, 0.f, 0.f, 0.f}, sd[4] = {0.f, 0.f, 0.f, 0.f};
#pragma unroll
            for (int q = 0; q < 4; ++q) {
                float4 hv = *reinterpret_cast<const float4*>(hp + q * 4);
#pragma unroll
                for (int hd = 0; hd < 4; ++hd) {
                    const float* wa = &wsdL[0][hd][p * 16 + q * 4];
                    const float* wb = &wsdL[1][hd][p * 16 + q * 4];
                    ss[hd] += hv.x * wa[0] + hv.y * wa[1] + hv.z * wa[2] + hv.w * wa[3];
                    sd[hd] += hv.x * wb[0] + hv.y * wb[1] + hv.z * wb[2] + hv.w * wb[3];
                }
            }
#pragma unroll
            for (int off = 1; off < 8; off <<= 1)
#pragma unroll
                for (int hd = 0; hd < 4; ++hd) {
                    ss[hd] += __shfl_xor(ss[hd], off);
                    sd[hd] += __shfl_xor(sd[hd], off);
                }
            if (p == 0) {
                *reinterpret_cast<float4*>(&s_src[(size_t)node * 4]) =
                    make_float4(ss[0] + cs[0], ss[1] + cs[1], ss[2] + cs[2], ss[3] + cs[3]);
                *reinterpret_cast<float4*>(&s_dst[(size_t)node * 4]) =
                    make_float4(sd[0] + cs[4], sd[1] + cs[5], sd[2] + cs[6], sd[3] + cs[7]);
            }
        }
    } else {
        int i = ((bid - 1 - scoreBlocks) * 256 + t) * 4;
        if (i < N * 4)
            *reinterpret_cast<int4*>(&head4[i]) = make_int4(-1, -1, -1, -1);
    }
}

// ---- work: MFMA GEMM blocks + edge blocks (fused, independent) -------------
__global__ __launch_bounds__(256) void k_work(
        const float* __restrict__ h, const unsigned short* __restrict__ Wb16,
        const float* __restrict__ bias, unsigned short* __restrict__ zb16,
        const int* __restrict__ src, const int* __restrict__ dst,
        const float* __restrict__ ef, const float* __restrict__ att,
        const float* __restrict__ s_src, const float* __restrict__ s_dst,
        int* __restrict__ head4, int4* __restrict__ epkt,
        int N, int E, int gemmBlocks) {
    __shared__ short hS[16 * 64 * 8];    // 16 KB (gemm blocks only)
    const int t = threadIdx.x;
    const int bid = blockIdx.x;

    if (bid >= gemmBlocks) {
        // ---- edge: alpha (dense) + linked-list build (4 chains/node) ----
        int e = (bid - gemmBlocks) * 256 + t;
        if (e >= E) return;
        int s = src[e], d = dst[e];
        float fv = ef[e];
        // atomic FIRST: its round-trip overlaps the score gathers
        int prev = atomicExch(&head4[(size_t)d * 4 + (e & 3)], e);
        float4 ss = *reinterpret_cast<const float4*>(&s_src[(size_t)s * 4]);
        float4 sd = *reinterpret_cast<const float4*>(&s_dst[(size_t)d * 4]);
        float aE0 = att[64], aE1 = att[129], aE2 = att[194], aE3 = att[259];
        float sc0 = ss.x + sd.x + fv * aE0;
        float sc1 = ss.y + sd.y + fv * aE1;
        float sc2 = ss.z + sd.z + fv * aE2;
        float sc3 = ss.w + sd.w + fv * aE3;
        sc0 = sc0 >= 0.f ? sc0 : 0.2f * sc0;  sc1 = sc1 >= 0.f ? sc1 : 0.2f * sc1;
        sc2 = sc2 >= 0.f ? sc2 : 0.2f * sc2;  sc3 = sc3 >= 0.f ? sc3 : 0.2f * sc3;
        float a0 = expf(fminf(fmaxf(sc0, -20.f), 20.f));
        float a1 = expf(fminf(fmaxf(sc1, -20.f), 20.f));
        float a2 = expf(fminf(fmaxf(sc2, -20.f), 20.f));
        float a3 = expf(fminf(fmaxf(sc3, -20.f), 20.f));
        epkt[e] = make_int4(s, prev,
            (int)(((unsigned)f2bf(a1) << 16) | f2bf(a0)),
            (int)(((unsigned)f2bf(a3) << 16) | f2bf(a2)));
        return;
    }

    // ---- GEMM block: 64 nodes x 64 cols (bid&1 selects col half) ----
    const int by = bid & 1;
    const int n0 = (bid >> 1) * 64;
    const int obase = by * 64;
#pragma unroll
    for (int q = 0; q < 8; ++q) {
        int f = q * 256 + t;
        int nd = f >> 5;
        int k4 = (f & 31) * 4;
        int ks = k4 >> 5, rr = k4 & 31;
        int half = rr >> 4, g = (rr & 15) >> 2;
        int kg = ks * 4 + g;
        int slot = kg * 64 + (nd ^ (kg & 7));
        int hn = n0 + nd; if (hn > N - 1) hn = N - 1;
        float4 v = *reinterpret_cast<const float4*>(&h[(size_t)hn * 128 + k4]);
        uint2 pk = make_uint2(((unsigned)f2bf(v.y) << 16) | f2bf(v.x),
                              ((unsigned)f2bf(v.w) << 16) | f2bf(v.z));
        *reinterpret_cast<uint2*>(&hS[slot * 8 + half * 4]) = pk;
    }
    __syncthreads();

    const int wv = t >> 6, l = t & 63;
    const int la = l & 15, lb = l >> 4;
    const int nbase = wv * 16;
    const int node = n0 + nbase + la;

    bf16x8 hfr[4];
#pragma unroll
    for (int ks = 0; ks < 4; ++ks) {
        int kg = ks * 4 + lb;
        int slot = kg * 64 + ((nbase + la) ^ (kg & 7));
        hfr[ks] = *reinterpret_cast<const bf16x8*>(&hS[slot * 8]);
    }

#pragma unroll
    for (int ot = 0; ot < 4; ++ot) {
        f32x4 acc = {0.f, 0.f, 0.f, 0.f};
#pragma unroll
        for (int ks = 0; ks < 4; ++ks) {
            int kg = ks * 4 + lb;
            bf16x8 wfr = *reinterpret_cast<const bf16x8*>(
                &Wb16[((size_t)kg * 128 + obase + ot * 16 + la) * 8]);
            acc = __builtin_amdgcn_mfma_f32_16x16x32_bf16(wfr, hfr[ks], acc, 0, 0, 0);
        }
        int colb = obase + ot * 16 + lb * 4;
        float4 bq = *reinterpret_cast<const float4*>(&bias[colb]);
        if (node < N) {
            uint2 pk = make_uint2(
                ((unsigned)f2bf(acc[1] + bq.y) << 16) | f2bf(acc[0] + bq.x),
                ((unsigned)f2bf(acc[3] + bq.w) << 16) | f2bf(acc[2] + bq.z));
            *reinterpret_cast<uint2*>(&zb16[(size_t)node * 128 + colb]) = pk;
        }
    }
}

// ---- fused: 4-chain walk aggregate + residual + LN + ELU -------------------
// 8 nodes per wave (8 lanes/node, 16 channels/lane); 4 chains per node.
// 128-thread blocks (2 waves, 16 nodes) — r17's proven optimum.
__global__ __launch_bounds__(128) void k_agg_final(const int* __restrict__ head4,
                                                   const int4* __restrict__ epkt,
                                                   const uint4* __restrict__ zb4,
                                                   const float* __restrict__ g,
                                                   const float* __restrict__ bparm,
                                                   float* __restrict__ out, int N) {
    int wave = threadIdx.x >> 6, lane = threadIdx.x & 63;
    int l8 = lane & 7;
    int n = blockIdx.x * 16 + wave * 8 + (lane >> 3);
    if (n >= N) return;
    const int hd = l8 >> 1;             // head of channels l8*16..+15
    int4 eh = *reinterpret_cast<const int4*>(&head4[(size_t)n * 4]);
    int e0 = eh.x, e1 = eh.y, e2 = eh.z, e3 = eh.w;
    float X0 = 0.f, X1 = 0.f, X2 = 0.f, X3 = 0.f;
    float X4 = 0.f, X5 = 0.f, X6 = 0.f, X7 = 0.f;
    float X8 = 0.f, X9 = 0.f, Xa = 0.f, Xb = 0.f;
    float Xc = 0.f, Xd = 0.f, Xe = 0.f, Xf = 0.f;
    float da = 0.f;
#define UNPK(P, AV) { unsigned u = (hd & 2) ? (unsigned)(P).w : (unsigned)(P).z; \
    AV = (hd & 1) ? bfH(u) : bfL(u); }
#define STEP(EV) if (EV != -1) { \
        int4 p = epkt[EV]; \
        uint4 q0 = zb4[(size_t)p.x * 16 + l8 * 2]; \
        uint4 q1 = zb4[(size_t)p.x * 16 + l8 * 2 + 1]; \
        float a; UNPK(p, a) \
        X0 += bfL(q0.x) * a; X1 += bfH(q0.x) * a; \
        X2 += bfL(q0.y) * a; X3 += bfH(q0.y) * a; \
        X4 += bfL(q0.z) * a; X5 += bfH(q0.z) * a; \
        X6 += bfL(q0.w) * a; X7 += bfH(q0.w) * a; \
        X8 += bfL(q1.x) * a; X9 += bfH(q1.x) * a; \
        Xa += bfL(q1.y) * a; Xb += bfH(q1.y) * a; \
        Xc += bfL(q1.z) * a; Xd += bfH(q1.z) * a; \
        Xe += bfL(q1.w) * a; Xf += bfH(q1.w) * a; \
        da += a; EV = p.y; }
    while (((e0 & e1) & (e2 & e3)) != -1) {
        STEP(e0) STEP(e1) STEP(e2) STEP(e3)
    }
#undef STEP
#undef UNPK

    float inv = 1.f / (da + 1e-6f);
    uint4 qz0 = zb4[(size_t)n * 16 + l8 * 2];
    uint4 qz1 = zb4[(size_t)n * 16 + l8 * 2 + 1];
    float x0 = X0 * inv + bfL(qz0.x), x1 = X1 * inv + bfH(qz0.x);
    float x2 = X2 * inv + bfL(qz0.y), x3 = X3 * inv + bfH(qz0.y);
    float x4 = X4 * inv + bfL(qz0.z), x5 = X5 * inv + bfH(qz0.z);
    float x6 = X6 * inv + bfL(qz0.w), x7 = X7 * inv + bfH(qz0.w);
    float x8 = X8 * inv + bfL(qz1.x), x9 = X9 * inv + bfH(qz1.x);
    float xa = Xa * inv + bfL(qz1.y), xb = Xb * inv + bfH(qz1.y);
    float xc = Xc * inv + bfL(qz1.z), xd = Xd * inv + bfH(qz1.z);
    float xe = Xe * inv + bfL(qz1.w), xf = Xf * inv + bfH(qz1.w);
    float s = (((x0 + x1) + (x2 + x3)) + ((x4 + x5) + (x6 + x7)))
            + (((x8 + x9) + (xa + xb)) + ((xc + xd) + (xe + xf)));
#pragma unroll
    for (int off = 1; off < 8; off <<= 1) s += __shfl_xor(s, off);
    float mu = s * (1.f / 128.f);
    float d0 = x0 - mu, d1 = x1 - mu, d2 = x2 - mu, d3 = x3 - mu;
    float d4 = x4 - mu, d5 = x5 - mu, d6 = x6 - mu, d7 = x7 - mu;
    float d8 = x8 - mu, d9 = x9 - mu, dA = xa - mu, dB = xb - mu;
    float dC = xc - mu, dD = xd - mu, dE = xe - mu, dF = xf - mu;
    float q = (((d0 * d0 + d1 * d1) + (d2 * d2 + d3 * d3))
             + ((d4 * d4 + d5 * d5) + (d6 * d6 + d7 * d7)))
            + (((d8 * d8 + d9 * d9) + (dA * dA + dB * dB))
             + ((dC * dC + dD * dD) + (dE * dE + dF * dF)));
#pragma unroll
    for (int off = 1; off < 8; off <<= 1) q += __shfl_xor(q, off);
    float rstd = rsqrtf(q * (1.f / 128.f) + 1e-5f);
    const int c = l8 * 16;
    float dv[16] = {d0, d1, d2, d3, d4, d5, d6, d7, d8, d9, dA, dB, dC, dD, dE, dF};
#pragma unroll
    for (int qb = 0; qb < 4; ++qb) {
        float4 gg = *reinterpret_cast<const float4*>(&g[c + qb * 4]);
        float4 bb = *reinterpret_cast<const float4*>(&bparm[c + qb * 4]);
        float y0 = dv[qb * 4 + 0] * rstd * gg.x + bb.x;
        float y1 = dv[qb * 4 + 1] * rstd * gg.y + bb.y;
        float y2 = dv[qb * 4 + 2] * rstd * gg.z + bb.z;
        float y3 = dv[qb * 4 + 3] * rstd * gg.w + bb.w;
        y0 = y0 > 0.f ? y0 : expf(y0) - 1.f;
        y1 = y1 > 0.f ? y1 : expf(y1) - 1.f;
        y2 = y2 > 0.f ? y2 : expf(y2) - 1.f;
        y3 = y3 > 0.f ? y3 : expf(y3) - 1.f;
        *reinterpret_cast<float4*>(&out[(size_t)n * 128 + c + qb * 4]) =
            make_float4(y0, y1, y2, y3);
    }
}

extern "C" void kernel_launch(void* const* d_in, const int* in_sizes, int n_in,
                              void* d_out, int out_size, void* d_ws, size_t ws_size,
                              hipStream_t stream) {
    const float* h   = (const float*)d_in[0];
    const int*   ei  = (const int*)d_in[1];
    const float* ef  = (const float*)d_in[2];
    const float* Ww  = (const float*)d_in[3];
    const float* Wb  = (const float*)d_in[4];
    const float* att = (const float*)d_in[5];
    const float* lng = (const float*)d_in[6];
    const float* lnb = (const float*)d_in[7];
    float* out = (float*)d_out;

    const int N = in_sizes[0] / 128;   // 50000
    const int E = in_sizes[1] / 2;     // 800000
    const int* src = ei;
    const int* dst = ei + E;

    char* ws = (char*)d_ws;
    unsigned short* zb16   = (unsigned short*)ws; ws += (size_t)N * 128 * 2;
    unsigned short* Wb16   = (unsigned short*)ws; ws += (size_t)128 * 128 * 2;
    float*          s_src  = (float*)ws;          ws += (size_t)N * 4 * 4;
    float*          s_dst  = (float*)ws;          ws += (size_t)N * 4 * 4;
    int*            head4  = (int*)ws;            ws += (size_t)N * 4 * 4;
    int4*           epkt   = (int4*)ws;           ws += (size_t)E * 16;

    const int scoreBlocks = (N + SCORE_NPB - 1) / SCORE_NPB;   // 391
    const int headBlocks  = (N + 255) / 256;                   // 196
    k_prep<<<1 + scoreBlocks + headBlocks, 256, 0, stream>>>(
        Ww, Wb, att, h, Wb16, s_src, s_dst, head4, N, scoreBlocks);

    const int gemmBlocks = ((N + 63) / 64) * 2;   // 1564
    const int edgeBlocks = (E + 255) / 256;       // 3125
    k_work<<<gemmBlocks + edgeBlocks, 256, 0, stream>>>(
        h, Wb16, Wb, zb16, src, dst, ef, att, s_src, s_dst, head4, epkt,
        N, E, gemmBlocks);
    k_agg_final<<<(N + 15) / 16, 128, 0, stream>>>(head4, epkt,
                                                   (const uint4*)zb16, lng, lnb, out, N);
}